// Round 12
// baseline (308.576 us; speedup 1.0000x reference)
//
#include <hip/hip_runtime.h>
#include <hip/hip_bf16.h>
#include <math.h>

// Problem constants
constexpr int Bc  = 2;
constexpr int Tc  = 2048;
constexpr int Dc  = 768;
constexpr int Hc  = 12;
constexpr int DHc = 64;
constexpr int M_ROWS = Bc * Tc;        // 4096
constexpr int D3  = 3 * Dc;            // 2304
constexpr int D4  = 4 * Dc;            // 3072

typedef __attribute__((ext_vector_type(8))) short short8;   // 8 bf16 (4 VGPRs)
typedef __attribute__((ext_vector_type(4))) float f32x4;    // MFMA acc

__device__ __forceinline__ unsigned short f2bf(float v) {
    union { __hip_bfloat16 b; unsigned short u; } cv;
    cv.b = __float2bfloat16(v);
    return cv.u;
}
__device__ __forceinline__ float bf2f(unsigned short u) {
    union { __hip_bfloat16 b; unsigned short u; } cv;
    cv.u = u;
    return __bfloat162float(cv.b);
}
__device__ __forceinline__ void bsplit(float v, unsigned short& h, unsigned short& l) {
    h = f2bf(v);
    l = f2bf(v - bf2f(h));
}

__device__ __forceinline__ float gelu_f(float x) {
    const float c = 0.79788456080286535588f; // sqrt(2/pi)
    return 0.5f * x * (1.0f + tanhf(c * (x + 0.044715f * x * x * x)));
}

// Async global->LDS, 16B per lane (LDS dest = wave-uniform base + lane*16).
__device__ __forceinline__ void glds16(const unsigned short* g, unsigned short* l) {
    __builtin_amdgcn_global_load_lds(
        (const __attribute__((address_space(1))) void*)g,
        (__attribute__((address_space(3))) void*)l, 16, 0, 0);
}

// ---------------------------------------------------------------------------
// Fused prepare: x cast + all 4 weight transpose-casts in ONE dispatch.
// ---------------------------------------------------------------------------
__device__ __forceinline__ void tcast8(
    const float* __restrict__ w, int ldw,
    unsigned short* __restrict__ th, int K, int N, int idx)
{
    const int n  = idx % N;
    const int k0 = (idx / N) * 8;
    unsigned short hv[8];
#pragma unroll
    for (int j = 0; j < 8; ++j)
        hv[j] = f2bf(w[(size_t)(k0 + j) * ldw + n]);
    const size_t o = (size_t)n * K + k0;
    *(ushort4*)(th + o)     = make_ushort4(hv[0], hv[1], hv[2], hv[3]);
    *(ushort4*)(th + o + 4) = make_ushort4(hv[4], hv[5], hv[6], hv[7]);
}

__global__ __launch_bounds__(256) void prepare_kernel(
    const float* __restrict__ x,
    const float* __restrict__ w_qkv, const float* __restrict__ w_proj,
    const float* __restrict__ w_fc,  const float* __restrict__ w_out,
    unsigned short* __restrict__ xh,
    unsigned short* __restrict__ wqkvT, unsigned short* __restrict__ wprojT,
    unsigned short* __restrict__ wfcT,  unsigned short* __restrict__ woutT)
{
    int id = blockIdx.x * 256 + threadIdx.x;
    if (id < 786432) {
        const float4 v = *(const float4*)(x + (size_t)id * 4);
        *(ushort4*)(xh + (size_t)id * 4) =
            make_ushort4(f2bf(v.x), f2bf(v.y), f2bf(v.z), f2bf(v.w));
        return;
    }
    id -= 786432;
    if (id < 221184) { tcast8(w_qkv, D3, wqkvT, Dc, D3, id); return; }
    id -= 221184;
    if (id < 73728)  { tcast8(w_proj, Dc, wprojT, Dc, Dc, id); return; }
    id -= 73728;
    if (id < 294912) { tcast8(w_fc, D4, wfcT, Dc, D4, id); return; }
    id -= 294912;
    tcast8(w_out, Dc, woutT, D4, Dc, id);
}

// ---------------------------------------------------------------------------
// R0-proven bf16 MFMA GEMM, BK=64, single-buffered, TN-parameterized.
// Session-measured optimum (R8 = 300.1 µs): TN=128 for big-N GEMMs
// (qkv, fc), TN=64 for small-N (proj, out). Falsified alternatives:
// dbuf/counted-vmcnt/8-phase/256² (R1/R2/R4/R5 regressed — K and grids too
// small for deep pipelines); TN=64 everywhere (R9, +9 µs re-read cost);
// dead-row tile skip (R11, null — len[1]~2048 for this seed).
// MODE: 0 = fp32 out (+bias) | 1 = gelu -> bf16 out (+bias) | 3 = bf16 out
// ---------------------------------------------------------------------------
template <int TM, int TN, int MODE>
__global__ __launch_bounds__(256) void gemm_bf16(
    const unsigned short* __restrict__ A,
    const unsigned short* __restrict__ B,
    const float* __restrict__ bias,
    float* __restrict__ C, unsigned short* __restrict__ Cb,
    int M, int N, int K)
{
    constexpr int MT = TM / 32;              // m-tiles per wave
    constexpr int NT = TN / 32;              // n-tiles per wave
    __shared__ unsigned short Ash[TM * 64];
    __shared__ unsigned short Bsh[TN * 64];

    const int tid  = threadIdx.x;
    const int n0   = blockIdx.x * TN;
    const int m0   = blockIdx.y * TM;
    const int wave = tid >> 6;
    const int lane = tid & 63;
    const int wm   = (wave >> 1) * (TM / 2);
    const int wn   = (wave & 1) * (TN / 2);
    const int lrow = lane & 15;
    const int quad = lane >> 4;
    const int swz  = lrow & 7;               // frag-read row swizzle key

    f32x4 acc[MT][NT];
    const f32x4 zero = {0.f, 0.f, 0.f, 0.f};
#pragma unroll
    for (int i = 0; i < MT; ++i)
#pragma unroll
        for (int j = 0; j < NT; ++j) acc[i][j] = zero;

    // staging: one glds16 issue covers 8 rows x 128 B. lane -> (row, chunk).
    const int l8r  = lane >> 3;              // 0..7 row within issue
    const int csel = ((lane & 7) ^ l8r) * 8; // swizzled global chunk (shorts)

    for (int ks = 0; ks < K; ks += 64) {
        __syncthreads();
#pragma unroll
        for (int j = 0; j < TM / 32; ++j) {
            const int rbase = wave * (TM / 4) + j * 8;
            const size_t g = (size_t)(m0 + rbase + l8r) * K + ks + csel;
            glds16(A + g, &Ash[rbase * 64]);
        }
#pragma unroll
        for (int j = 0; j < TN / 32; ++j) {
            const int rbase = wave * (TN / 4) + j * 8;
            const size_t g = (size_t)(n0 + rbase + l8r) * K + ks + csel;
            glds16(B + g, &Bsh[rbase * 64]);
        }
        __syncthreads();

#pragma unroll
        for (int kk = 0; kk < 2; ++kk) {
            short8 fa[MT], fb[NT];
            const int cl = kk * 4 + quad;    // logical chunk
            const int pc = (cl ^ swz) * 8;   // physical chunk offset (shorts)
#pragma unroll
            for (int t = 0; t < MT; ++t)
                fa[t] = *(const short8*)&Ash[(wm + t * 16 + lrow) * 64 + pc];
#pragma unroll
            for (int t = 0; t < NT; ++t)
                fb[t] = *(const short8*)&Bsh[(wn + t * 16 + lrow) * 64 + pc];
#pragma unroll
            for (int mt = 0; mt < MT; ++mt)
#pragma unroll
                for (int nt = 0; nt < NT; ++nt)
                    acc[mt][nt] = __builtin_amdgcn_mfma_f32_16x16x32_bf16(
                        fa[mt], fb[nt], acc[mt][nt], 0, 0, 0);
        }
    }

#pragma unroll
    for (int mt = 0; mt < MT; ++mt) {
        const int rowb = m0 + wm + mt * 16 + quad * 4;
#pragma unroll
        for (int nt = 0; nt < NT; ++nt) {
            const int col = n0 + wn + nt * 16 + lrow;
            const float bv = bias[col];
#pragma unroll
            for (int r = 0; r < 4; ++r) {
                const size_t ci = (size_t)(rowb + r) * N + col;
                if (MODE == 0) {
                    C[ci] = acc[mt][nt][r] + bv;
                } else if (MODE == 1) {
                    Cb[ci] = f2bf(gelu_f(acc[mt][nt][r] + bv));
                } else { // MODE 3
                    Cb[ci] = f2bf(acc[mt][nt][r] + bv);
                }
            }
        }
    }
}

// ---------------------------------------------------------------------------
// bf16 MFMA flash attention, v8 (session-best attn: 65.6-65.8 µs measured):
// K/V double-buffer -> ONE barrier per K-tile, setprio around MFMA
// clusters, PS2=68 conflict-reduced P stores, exp2 softmax, Vt swizzle.
// Eliminated hypotheses: occupancy (R6 split-K null), bank conflicts
// (R8: counter -9%, dur flat), barriers (R10: -3.5 µs, the residual).
// Remaining gap is the serial per-tile dependency chain — would need a
// full 8-wave/32x32 restructure to attack.
// ---------------------------------------------------------------------------
constexpr int KS  = 72;  // K/V LDS row stride (shorts): 144B rows, 16B-aligned
constexpr int PS2 = 68;  // P LDS row stride (shorts): 136B rows, 8B-aligned

__global__ __launch_bounds__(256) void flash_attn_bf16(
    const unsigned short* __restrict__ qkv,
    const int* __restrict__ lengths,
    unsigned short* __restrict__ oh)
{
    __shared__ unsigned short Kh[2][64 * KS];
    __shared__ unsigned short Vt[2][64 * KS];  // V^T: [d][k], chunk-swizzled
    __shared__ unsigned short PfU[64 * PS2];   // P bf16, wave-private strips

    const int tid  = threadIdx.x;
    const int wave = tid >> 6;
    const int lane = tid & 63;
    const int m    = lane & 15;
    const int quad = lane >> 4;

    const int nqt = Tc / 64;                  // 32
    const int qt  = blockIdx.x % nqt;
    const int bh  = blockIdx.x / nqt;
    const int hh  = bh % Hc;
    const int b   = bh / Hc;
    const int len = lengths[b];
    const int q0  = qt * 64;
    const size_t rs = (size_t)D3;
    const unsigned short* base = qkv + (size_t)b * Tc * rs;
    const int qcol = hh * DHc;
    const int kcol = Dc + hh * DHc;
    const int vcol = 2 * Dc + hh * DHc;

    // ---- q-tile fully masked: write zeros, done ----
    if (q0 >= len) {
#pragma unroll
        for (int r = 0; r < 4; ++r) {
            const int qrow = q0 + wave * 16 + quad * 4 + r;
            const size_t ob = (size_t)(b * Tc + qrow) * Dc + hh * DHc + m;
#pragma unroll
            for (int nt = 0; nt < 4; ++nt) oh[ob + nt * 16] = 0;
        }
        return;
    }

    const int ktEnd = (min(len, Tc) + 63) >> 6;   // skip fully-masked K tiles

    // ---- preload Q fragments (A-layout), pre-scaled by log2(e) ----
    short8 Qf[2];
#pragma unroll
    for (int ch = 0; ch < 2; ++ch) {
        const size_t ga = (size_t)(q0 + wave * 16 + m) * rs + qcol + ch * 32 + quad * 8;
        const short8 q8 = *(const short8*)&base[ga];
        short8 qs;
#pragma unroll
        for (int j = 0; j < 8; ++j)
            qs[j] = (short)f2bf(bf2f((unsigned short)q8[j]) * 1.44269504088896f);
        Qf[ch] = qs;
    }

    f32x4 Oacc[4];
    const f32x4 zero = {0.f, 0.f, 0.f, 0.f};
#pragma unroll
    for (int nt = 0; nt < 4; ++nt) Oacc[nt] = zero;
    float lrow[4] = {0.f, 0.f, 0.f, 0.f};     // per-lane partial row sums

    // staging maps
    const int kr0 = tid >> 3,          kc0 = (tid & 7) * 8;          // rows 0..31
    const int kr1 = (tid + 256) >> 3,  kc1 = ((tid + 256) & 7) * 8;  // rows 32..63
    const int pk  = (tid >> 4) * 4;      // V patch: k-base (0,4,8,12)
    const int pd  = (tid & 15) * 4;      // V patch: d-base (0..60)
    // Vt swizzle: phys chunk = (k>>3) ^ ((d>>2)&7); uniform per thread-patch.
    const int vswz = ((pk >> 3) ^ ((pd >> 2) & 7)) * 8 + (pk & 7);

    // prefetch registers
    short8  pK0, pK1;
    ushort4 pV0, pV1, pV2, pV3;
    {   // load tile 0
        pK0 = *(const short8*)&base[(size_t)kr0 * rs + kcol + kc0];
        pK1 = *(const short8*)&base[(size_t)kr1 * rs + kcol + kc1];
        pV0 = *(const ushort4*)&base[(size_t)(pk + 0) * rs + vcol + pd];
        pV1 = *(const ushort4*)&base[(size_t)(pk + 1) * rs + vcol + pd];
        pV2 = *(const ushort4*)&base[(size_t)(pk + 2) * rs + vcol + pd];
        pV3 = *(const ushort4*)&base[(size_t)(pk + 3) * rs + vcol + pd];
    }

    for (int kt = 0; kt < ktEnd; ++kt) {
        const int kbase = kt * 64;
        const int c = kt & 1;

        // ---- stage prefetched K/V to LDS buf[c] (Vt chunk-swizzled) ----
        *(short8*)&Kh[c][kr0 * KS + kc0] = pK0;
        *(short8*)&Kh[c][kr1 * KS + kc1] = pK1;
        *(ushort4*)&Vt[c][(pd + 0) * KS + vswz] = make_ushort4(pV0.x, pV1.x, pV2.x, pV3.x);
        *(ushort4*)&Vt[c][(pd + 1) * KS + vswz] = make_ushort4(pV0.y, pV1.y, pV2.y, pV3.y);
        *(ushort4*)&Vt[c][(pd + 2) * KS + vswz] = make_ushort4(pV0.z, pV1.z, pV2.z, pV3.z);
        *(ushort4*)&Vt[c][(pd + 3) * KS + vswz] = make_ushort4(pV0.w, pV1.w, pV2.w, pV3.w);
        __syncthreads();   // single barrier per K-tile

        // ---- issue loads for tile kt+1 (fly under compute below) ----
        if (kt + 1 < ktEnd) {
            const int nb = kbase + 64;
            pK0 = *(const short8*)&base[(size_t)(nb + kr0) * rs + kcol + kc0];
            pK1 = *(const short8*)&base[(size_t)(nb + kr1) * rs + kcol + kc1];
            pV0 = *(const ushort4*)&base[(size_t)(nb + pk + 0) * rs + vcol + pd];
            pV1 = *(const ushort4*)&base[(size_t)(nb + pk + 1) * rs + vcol + pd];
            pV2 = *(const ushort4*)&base[(size_t)(nb + pk + 2) * rs + vcol + pd];
            pV3 = *(const ushort4*)&base[(size_t)(nb + pk + 3) * rs + vcol + pd];
        }

        // ---- S' = (Q*log2e) · K^T ----
        f32x4 S4[4];
#pragma unroll
        for (int nt = 0; nt < 4; ++nt) S4[nt] = zero;
        __builtin_amdgcn_s_setprio(1);
#pragma unroll
        for (int ch = 0; ch < 2; ++ch)
#pragma unroll
            for (int nt = 0; nt < 4; ++nt) {
                const short8 k8 = *(const short8*)&Kh[c][(nt * 16 + m) * KS + ch * 32 + quad * 8];
                S4[nt] = __builtin_amdgcn_mfma_f32_16x16x32_bf16(Qf[ch], k8, S4[nt], 0, 0, 0);
            }
        __builtin_amdgcn_s_setprio(0);

        // ---- mask invalid keys (exp2(-1e30) underflows to exact 0) ----
        if (kbase + 64 > len) {
#pragma unroll
            for (int nt = 0; nt < 4; ++nt)
                if (kbase + nt * 16 + m >= len) {
#pragma unroll
                    for (int r = 0; r < 4; ++r) S4[nt][r] = -1e30f;
                }
        }

        // ---- p = exp2(S'); accumulate partial l; store P (bf16) ----
        // store bank = 8*quad + 2r + m/2 (PS2=68) -> conflict-free
#pragma unroll
        for (int nt = 0; nt < 4; ++nt)
#pragma unroll
            for (int r = 0; r < 4; ++r) {
                const float p = __builtin_amdgcn_exp2f(S4[nt][r]);
                lrow[r] += p;
                PfU[(wave * 16 + quad * 4 + r) * PS2 + nt * 16 + m] = f2bf(p);
            }

        // ---- O += P · V (P read as 2x ushort4: rows are 8B-aligned) ----
        const int pbase = (wave * 16 + m) * PS2;
#pragma unroll
        for (int ch = 0; ch < 2; ++ch) {
            union { ushort4 u4[2]; short8 s8; } pu;
            pu.u4[0] = *(const ushort4*)&PfU[pbase + ch * 32 + quad * 8];
            pu.u4[1] = *(const ushort4*)&PfU[pbase + ch * 32 + quad * 8 + 4];
            const short8 P8 = pu.s8;
            __builtin_amdgcn_s_setprio(1);
#pragma unroll
            for (int nt = 0; nt < 4; ++nt) {
                const int pchunk = ((ch * 4 + quad) ^ ((nt * 4 + (m >> 2)) & 7)) * 8;
                const short8 v8 = *(const short8*)&Vt[c][(nt * 16 + m) * KS + pchunk];
                Oacc[nt] = __builtin_amdgcn_mfma_f32_16x16x32_bf16(P8, v8, Oacc[nt], 0, 0, 0);
            }
            __builtin_amdgcn_s_setprio(0);
        }
    }

    // ---- single end-of-loop row-sum reduction over the 16 m-lanes ----
#pragma unroll
    for (int r = 0; r < 4; ++r) {
#pragma unroll
        for (int sh = 8; sh >= 1; sh >>= 1)
            lrow[r] += __shfl_xor(lrow[r], sh);
    }

    // ---- epilogue: /l, zero invalid q rows, bf16 store ----
#pragma unroll
    for (int r = 0; r < 4; ++r) {
        const int qrow = q0 + wave * 16 + quad * 4 + r;
        const size_t ob = (size_t)(b * Tc + qrow) * Dc + hh * DHc + m;
        if (qrow < len) {
            const float inv = 1.0f / lrow[r];
#pragma unroll
            for (int nt = 0; nt < 4; ++nt)
                oh[ob + nt * 16] = f2bf(Oacc[nt][r] * inv);
        } else {
#pragma unroll
            for (int nt = 0; nt < 4; ++nt)
                oh[ob + nt * 16] = 0;
        }
    }
}

// ---------------------------------------------------------------------------
// LN1: (outh,outl) = split_bf16(LN(X + Y) * mask). X,Y fp32.
// Single-pass sum/sumsq (R8-proven, -15 µs vs two-pass).
// ---------------------------------------------------------------------------
__global__ __launch_bounds__(256) void ln_split_kernel(
    const float* __restrict__ X, const float* __restrict__ Y,
    const float* __restrict__ g, const float* __restrict__ beta,
    const int* __restrict__ lengths,
    unsigned short* __restrict__ outh, unsigned short* __restrict__ outl)
{
    __shared__ float red[8];
    const int row = blockIdx.x;
    const int b = row / Tc, t = row % Tc;
    const int len = lengths[b];
    const size_t basei = (size_t)row * Dc;
    const int tid = threadIdx.x;

    if (t >= len) {
        for (int j = tid; j < Dc; j += 256) { outh[basei + j] = 0; outl[basei + j] = 0; }
        return;
    }

    float v[3];
    float s = 0.f, s2 = 0.f;
#pragma unroll
    for (int j = 0; j < 3; ++j) {
        int idx = tid + j * 256;
        v[j] = X[basei + idx] + Y[basei + idx];
        s  += v[j];
        s2 += v[j] * v[j];
    }
    const int lane = tid % 64, wid = tid / 64;
#pragma unroll
    for (int sh = 32; sh >= 1; sh >>= 1) {
        s  += __shfl_xor(s, sh);
        s2 += __shfl_xor(s2, sh);
    }
    if (lane == 0) { red[wid] = s; red[4 + wid] = s2; }
    __syncthreads();
    s  = red[0] + red[1] + red[2] + red[3];
    s2 = red[4] + red[5] + red[6] + red[7];
    const float mu   = s * (1.0f / Dc);
    const float var  = s2 * (1.0f / Dc) - mu * mu;
    const float rstd = rsqrtf(var + 1e-5f);

#pragma unroll
    for (int j = 0; j < 3; ++j) {
        int idx = tid + j * 256;
        const float ov = (v[j] - mu) * rstd * g[idx] + beta[idx];
        unsigned short hh, ll;
        bsplit(ov, hh, ll);
        outh[basei + idx] = hh;
        outl[basei + idx] = ll;
    }
}

// ---------------------------------------------------------------------------
// LN2: out = LN((Xh+Xl) + Y) * mask, fp32 out. Y and out may alias (in-place).
// Single-pass sum/sumsq (R8-proven).
// ---------------------------------------------------------------------------
__global__ __launch_bounds__(256) void ln2_kernel(
    const unsigned short* __restrict__ Xh, const unsigned short* __restrict__ Xl,
    const float* Y,
    const float* __restrict__ g, const float* __restrict__ beta,
    const int* __restrict__ lengths, float* out)
{
    __shared__ float red[8];
    const int row = blockIdx.x;
    const int b = row / Tc, t = row % Tc;
    const int len = lengths[b];
    const size_t basei = (size_t)row * Dc;
    const int tid = threadIdx.x;

    if (t >= len) {
        for (int j = tid; j < Dc; j += 256) out[basei + j] = 0.f;
        return;
    }

    float v[3];
    float s = 0.f, s2 = 0.f;
#pragma unroll
    for (int j = 0; j < 3; ++j) {
        int idx = tid + j * 256;
        v[j] = bf2f(Xh[basei + idx]) + bf2f(Xl[basei + idx]) + Y[basei + idx];
        s  += v[j];
        s2 += v[j] * v[j];
    }
    const int lane = tid % 64, wid = tid / 64;
#pragma unroll
    for (int sh = 32; sh >= 1; sh >>= 1) {
        s  += __shfl_xor(s, sh);
        s2 += __shfl_xor(s2, sh);
    }
    if (lane == 0) { red[wid] = s; red[4 + wid] = s2; }
    __syncthreads();
    s  = red[0] + red[1] + red[2] + red[3];
    s2 = red[4] + red[5] + red[6] + red[7];
    const float mu   = s * (1.0f / Dc);
    const float var  = s2 * (1.0f / Dc) - mu * mu;
    const float rstd = rsqrtf(var + 1e-5f);

#pragma unroll
    for (int j = 0; j < 3; ++j) {
        int idx = tid + j * 256;
        out[basei + idx] = (v[j] - mu) * rstd * g[idx] + beta[idx];
    }
}

// ---------------------------------------------------------------------------
// Workspace plan (bytes; peak 51,904,512 — R0 layout):
//   [0, 18.87M)        : qkvh -> projo fp32 [0,12.58M) -> fH head
//   [18.87M, 25.17M)   : xh -> ah -> fH tail  (fH = [0,25.17M) [4096,3072])
//   [25.17M, 31.46M)   : nh | [31.46M, 37.75M) : nl
//   [37.75M, 41.29M)   : wqkvT | [41.29M, 42.47M) : wprojT
//   [42.47M, 47.19M)   : wfcT  | [47.19M, 51.91M) : woutT
// ---------------------------------------------------------------------------
extern "C" void kernel_launch(void* const* d_in, const int* in_sizes, int n_in,
                              void* d_out, int out_size, void* d_ws, size_t ws_size,
                              hipStream_t stream)
{
    const float* x      = (const float*)d_in[0];
    const int*   lens   = (const int*)  d_in[1];
    const float* w_qkv  = (const float*)d_in[2];
    const float* b_qkv  = (const float*)d_in[3];
    const float* w_proj = (const float*)d_in[4];
    const float* b_proj = (const float*)d_in[5];
    const float* ln1_g  = (const float*)d_in[6];
    const float* ln1_b  = (const float*)d_in[7];
    const float* w_fc   = (const float*)d_in[8];
    const float* b_fc   = (const float*)d_in[9];
    const float* w_out  = (const float*)d_in[10];
    const float* b_out  = (const float*)d_in[11];
    const float* ln2_g  = (const float*)d_in[12];
    const float* ln2_b  = (const float*)d_in[13];

    if (ws_size < 51904512) return;  // -> validation mismatch, not a crash

    char* ws = (char*)d_ws;
    unsigned short* qkvh  = (unsigned short*)(ws + 0);           // [4096,2304]
    unsigned short* xh    = (unsigned short*)(ws + 18874368);    // [4096,768]
    unsigned short* ah    = xh;                                  // attn out (xh dead)
    float*          projo = (float*)(ws + 0);                    // [4096,768] fp32
    unsigned short* fH    = (unsigned short*)(ws + 0);           // [4096,3072]
    unsigned short* nh    = (unsigned short*)(ws + 25165824);    // [4096,768]
    unsigned short* nl    = (unsigned short*)(ws + 31457280);
    unsigned short* wqkvT = (unsigned short*)(ws + 37748736);
    unsigned short* wprojT= (unsigned short*)(ws + 41287680);
    unsigned short* wfcT  = (unsigned short*)(ws + 42467328);
    unsigned short* woutT = (unsigned short*)(ws + 47185920);
    float*          mbuf  = (float*)d_out;

    const dim3 blk(256);

    // 0) fused prepare: x cast + all weight transposes
    prepare_kernel<<<dim3(6528), blk, 0, stream>>>(
        x, w_qkv, w_proj, w_fc, w_out, xh, wqkvT, wprojT, wfcT, woutT);

    // 1) qkv = x @ w_qkv + b_qkv -> bf16  (TM=64/TN=128: 1152 blocks)
    gemm_bf16<64, 128, 3><<<dim3(D3 / 128, M_ROWS / 64), blk, 0, stream>>>(
        xh, wqkvT, b_qkv, nullptr, qkvh, M_ROWS, D3, Dc);

    // 2) attention v8 -> ah (bf16)  (768 blocks)
    flash_attn_bf16<<<dim3(Bc * Hc * (Tc / 64)), blk, 0, stream>>>(qkvh, lens, ah);

    // 3) proj: projo = a @ w_proj + b_proj (fp32)  (TN=64: 768 blocks)
    gemm_bf16<64, 64, 0><<<dim3(Dc / 64, M_ROWS / 64), blk, 0, stream>>>(
        ah, wprojT, b_proj, projo, nullptr, M_ROWS, Dc, Dc);

    // 4) n = LN(x + projo) * mask -> (nh, nl)
    ln_split_kernel<<<dim3(M_ROWS), blk, 0, stream>>>(x, projo, ln1_g, ln1_b, lens, nh, nl);

    // 5) fc: fH = bf16(gelu(n @ w_fc + b_fc))  (TM=64/TN=128: 1536 blocks)
    gemm_bf16<64, 128, 1><<<dim3(D4 / 128, M_ROWS / 64), blk, 0, stream>>>(
        nh, wfcT, b_fc, nullptr, fH, M_ROWS, D4, Dc);

    // 6) m = fH @ w_out + b_out -> d_out (fp32), K=3072  (TN=64: 768 blocks)
    gemm_bf16<64, 64, 0><<<dim3(Dc / 64, M_ROWS / 64), blk, 0, stream>>>(
        fH, woutT, b_out, mbuf, nullptr, M_ROWS, Dc, D4);

    // 7) h = LN((nh+nl) + m) * mask -> d_out (in-place)
    ln2_kernel<<<dim3(M_ROWS), blk, 0, stream>>>(nh, nl, mbuf, ln2_g, ln2_b, lens,
                                                 (float*)d_out);
}

// Round 13
// 301.822 us; speedup vs baseline: 1.0224x; 1.0224x over previous
//
#include <hip/hip_runtime.h>
#include <hip/hip_bf16.h>
#include <math.h>

// Problem constants
constexpr int Bc  = 2;
constexpr int Tc  = 2048;
constexpr int Dc  = 768;
constexpr int Hc  = 12;
constexpr int DHc = 64;
constexpr int M_ROWS = Bc * Tc;        // 4096
constexpr int D3  = 3 * Dc;            // 2304
constexpr int D4  = 4 * Dc;            // 3072

typedef __attribute__((ext_vector_type(8))) short short8;   // 8 bf16 (4 VGPRs)
typedef __attribute__((ext_vector_type(4))) float f32x4;    // MFMA acc

__device__ __forceinline__ unsigned short f2bf(float v) {
    union { __hip_bfloat16 b; unsigned short u; } cv;
    cv.b = __float2bfloat16(v);
    return cv.u;
}
__device__ __forceinline__ float bf2f(unsigned short u) {
    union { __hip_bfloat16 b; unsigned short u; } cv;
    cv.u = u;
    return __bfloat162float(cv.b);
}
__device__ __forceinline__ void bsplit(float v, unsigned short& h, unsigned short& l) {
    h = f2bf(v);
    l = f2bf(v - bf2f(h));
}

__device__ __forceinline__ float gelu_f(float x) {
    const float c = 0.79788456080286535588f; // sqrt(2/pi)
    return 0.5f * x * (1.0f + tanhf(c * (x + 0.044715f * x * x * x)));
}

// Async global->LDS, 16B per lane (LDS dest = wave-uniform base + lane*16).
__device__ __forceinline__ void glds16(const unsigned short* g, unsigned short* l) {
    __builtin_amdgcn_global_load_lds(
        (const __attribute__((address_space(1))) void*)g,
        (__attribute__((address_space(3))) void*)l, 16, 0, 0);
}

// ---------------------------------------------------------------------------
// Fused prepare: x cast + all 4 weight transpose-casts in ONE dispatch.
// ---------------------------------------------------------------------------
__device__ __forceinline__ void tcast8(
    const float* __restrict__ w, int ldw,
    unsigned short* __restrict__ th, int K, int N, int idx)
{
    const int n  = idx % N;
    const int k0 = (idx / N) * 8;
    unsigned short hv[8];
#pragma unroll
    for (int j = 0; j < 8; ++j)
        hv[j] = f2bf(w[(size_t)(k0 + j) * ldw + n]);
    const size_t o = (size_t)n * K + k0;
    *(ushort4*)(th + o)     = make_ushort4(hv[0], hv[1], hv[2], hv[3]);
    *(ushort4*)(th + o + 4) = make_ushort4(hv[4], hv[5], hv[6], hv[7]);
}

__global__ __launch_bounds__(256) void prepare_kernel(
    const float* __restrict__ x,
    const float* __restrict__ w_qkv, const float* __restrict__ w_proj,
    const float* __restrict__ w_fc,  const float* __restrict__ w_out,
    unsigned short* __restrict__ xh,
    unsigned short* __restrict__ wqkvT, unsigned short* __restrict__ wprojT,
    unsigned short* __restrict__ wfcT,  unsigned short* __restrict__ woutT)
{
    int id = blockIdx.x * 256 + threadIdx.x;
    if (id < 786432) {
        const float4 v = *(const float4*)(x + (size_t)id * 4);
        *(ushort4*)(xh + (size_t)id * 4) =
            make_ushort4(f2bf(v.x), f2bf(v.y), f2bf(v.z), f2bf(v.w));
        return;
    }
    id -= 786432;
    if (id < 221184) { tcast8(w_qkv, D3, wqkvT, Dc, D3, id); return; }
    id -= 221184;
    if (id < 73728)  { tcast8(w_proj, Dc, wprojT, Dc, Dc, id); return; }
    id -= 73728;
    if (id < 294912) { tcast8(w_fc, D4, wfcT, Dc, D4, id); return; }
    id -= 294912;
    tcast8(w_out, Dc, woutT, D4, Dc, id);
}

// ---------------------------------------------------------------------------
// R0-proven bf16 MFMA GEMM, BK=64, single-buffered, TN-parameterized.
// Session-measured optimum (R8 = 300.1 µs): TN=128 for big-N GEMMs
// (qkv, fc), TN=64 for small-N (proj, out).
// MODE: 0 = fp32 out (+bias) | 1 = gelu -> bf16 out (+bias) | 3 = bf16 out
// ---------------------------------------------------------------------------
template <int TM, int TN, int MODE>
__global__ __launch_bounds__(256) void gemm_bf16(
    const unsigned short* __restrict__ A,
    const unsigned short* __restrict__ B,
    const float* __restrict__ bias,
    float* __restrict__ C, unsigned short* __restrict__ Cb,
    int M, int N, int K)
{
    constexpr int MT = TM / 32;              // m-tiles per wave
    constexpr int NT = TN / 32;              // n-tiles per wave
    __shared__ unsigned short Ash[TM * 64];
    __shared__ unsigned short Bsh[TN * 64];

    const int tid  = threadIdx.x;
    const int n0   = blockIdx.x * TN;
    const int m0   = blockIdx.y * TM;
    const int wave = tid >> 6;
    const int lane = tid & 63;
    const int wm   = (wave >> 1) * (TM / 2);
    const int wn   = (wave & 1) * (TN / 2);
    const int lrow = lane & 15;
    const int quad = lane >> 4;
    const int swz  = lrow & 7;               // frag-read row swizzle key

    f32x4 acc[MT][NT];
    const f32x4 zero = {0.f, 0.f, 0.f, 0.f};
#pragma unroll
    for (int i = 0; i < MT; ++i)
#pragma unroll
        for (int j = 0; j < NT; ++j) acc[i][j] = zero;

    // staging: one glds16 issue covers 8 rows x 128 B. lane -> (row, chunk).
    const int l8r  = lane >> 3;              // 0..7 row within issue
    const int csel = ((lane & 7) ^ l8r) * 8; // swizzled global chunk (shorts)

    for (int ks = 0; ks < K; ks += 64) {
        __syncthreads();
#pragma unroll
        for (int j = 0; j < TM / 32; ++j) {
            const int rbase = wave * (TM / 4) + j * 8;
            const size_t g = (size_t)(m0 + rbase + l8r) * K + ks + csel;
            glds16(A + g, &Ash[rbase * 64]);
        }
#pragma unroll
        for (int j = 0; j < TN / 32; ++j) {
            const int rbase = wave * (TN / 4) + j * 8;
            const size_t g = (size_t)(n0 + rbase + l8r) * K + ks + csel;
            glds16(B + g, &Bsh[rbase * 64]);
        }
        __syncthreads();

#pragma unroll
        for (int kk = 0; kk < 2; ++kk) {
            short8 fa[MT], fb[NT];
            const int cl = kk * 4 + quad;    // logical chunk
            const int pc = (cl ^ swz) * 8;   // physical chunk offset (shorts)
#pragma unroll
            for (int t = 0; t < MT; ++t)
                fa[t] = *(const short8*)&Ash[(wm + t * 16 + lrow) * 64 + pc];
#pragma unroll
            for (int t = 0; t < NT; ++t)
                fb[t] = *(const short8*)&Bsh[(wn + t * 16 + lrow) * 64 + pc];
#pragma unroll
            for (int mt = 0; mt < MT; ++mt)
#pragma unroll
                for (int nt = 0; nt < NT; ++nt)
                    acc[mt][nt] = __builtin_amdgcn_mfma_f32_16x16x32_bf16(
                        fa[mt], fb[nt], acc[mt][nt], 0, 0, 0);
        }
    }

#pragma unroll
    for (int mt = 0; mt < MT; ++mt) {
        const int rowb = m0 + wm + mt * 16 + quad * 4;
#pragma unroll
        for (int nt = 0; nt < NT; ++nt) {
            const int col = n0 + wn + nt * 16 + lrow;
            const float bv = bias[col];
#pragma unroll
            for (int r = 0; r < 4; ++r) {
                const size_t ci = (size_t)(rowb + r) * N + col;
                if (MODE == 0) {
                    C[ci] = acc[mt][nt][r] + bv;
                } else if (MODE == 1) {
                    Cb[ci] = f2bf(gelu_f(acc[mt][nt][r] + bv));
                } else { // MODE 3
                    Cb[ci] = f2bf(acc[mt][nt][r] + bv);
                }
            }
        }
    }
}

// ---------------------------------------------------------------------------
// bf16 MFMA flash attention, v9 = v8 + SWAPPED QK^T -> P fully in-register.
// mfma(k8, Qf) computes S^T: each lane holds one full P row (q=wave*16+m,
// k=nt*16+quad*4+r) by the C/D map col=lane&15,row=quad*4+r. After exp2 the
// PV A-fragment (P[q=m-row][k=ch*32+quad*8+0..7]) is assembled with 16
// __shfl + 8 selects (bf16x2-packed) — the P LDS roundtrip (16 b16 stores +
// lgkm wait + 4 b64 reads per tile) is DELETED, and so is the PfU buffer
// (LDS 45.6 -> 36.9 KB => 4 blocks/CU). A/B fragment lane maps are
// identical (idx=lane&15, k=quad*8+j) so the operand swap is layout-safe;
// V reads, PV output layout, and the O epilogue are unchanged. l becomes a
// per-lane row sum + 2-shfl quad reduction; epilogue pulls l via 4 shfls.
// ---------------------------------------------------------------------------
constexpr int KS  = 72;  // K/V LDS row stride (shorts): 144B rows, 16B-aligned

__global__ __launch_bounds__(256) void flash_attn_bf16(
    const unsigned short* __restrict__ qkv,
    const int* __restrict__ lengths,
    unsigned short* __restrict__ oh)
{
    __shared__ unsigned short Kh[2][64 * KS];
    __shared__ unsigned short Vt[2][64 * KS];  // V^T: [d][k], chunk-swizzled

    const int tid  = threadIdx.x;
    const int wave = tid >> 6;
    const int lane = tid & 63;
    const int m    = lane & 15;
    const int quad = lane >> 4;

    const int nqt = Tc / 64;                  // 32
    const int qt  = blockIdx.x % nqt;
    const int bh  = blockIdx.x / nqt;
    const int hh  = bh % Hc;
    const int b   = bh / Hc;
    const int len = lengths[b];
    const int q0  = qt * 64;
    const size_t rs = (size_t)D3;
    const unsigned short* base = qkv + (size_t)b * Tc * rs;
    const int qcol = hh * DHc;
    const int kcol = Dc + hh * DHc;
    const int vcol = 2 * Dc + hh * DHc;

    // ---- q-tile fully masked: write zeros, done ----
    if (q0 >= len) {
#pragma unroll
        for (int r = 0; r < 4; ++r) {
            const int qrow = q0 + wave * 16 + quad * 4 + r;
            const size_t ob = (size_t)(b * Tc + qrow) * Dc + hh * DHc + m;
#pragma unroll
            for (int nt = 0; nt < 4; ++nt) oh[ob + nt * 16] = 0;
        }
        return;
    }

    const int ktEnd = (min(len, Tc) + 63) >> 6;   // skip fully-masked K tiles

    // ---- preload Q fragments (B-operand layout = same lane map), pre-scaled
    //      by log2(e) ----
    short8 Qf[2];
#pragma unroll
    for (int ch = 0; ch < 2; ++ch) {
        const size_t ga = (size_t)(q0 + wave * 16 + m) * rs + qcol + ch * 32 + quad * 8;
        const short8 q8 = *(const short8*)&base[ga];
        short8 qs;
#pragma unroll
        for (int j = 0; j < 8; ++j)
            qs[j] = (short)f2bf(bf2f((unsigned short)q8[j]) * 1.44269504088896f);
        Qf[ch] = qs;
    }

    f32x4 Oacc[4];
    const f32x4 zero = {0.f, 0.f, 0.f, 0.f};
#pragma unroll
    for (int nt = 0; nt < 4; ++nt) Oacc[nt] = zero;
    float lsum = 0.f;                          // full row sum for q=wave*16+m

    // staging maps
    const int kr0 = tid >> 3,          kc0 = (tid & 7) * 8;          // rows 0..31
    const int kr1 = (tid + 256) >> 3,  kc1 = ((tid + 256) & 7) * 8;  // rows 32..63
    const int pk  = (tid >> 4) * 4;      // V patch: k-base (0,4,8,12)
    const int pd  = (tid & 15) * 4;      // V patch: d-base (0..60)
    // Vt swizzle: phys chunk = (k>>3) ^ ((d>>2)&7); uniform per thread-patch.
    const int vswz = ((pk >> 3) ^ ((pd >> 2) & 7)) * 8 + (pk & 7);

    // P-exchange constants
    const int qs  = 2 * (quad & 1);            // source quad base
    const bool qh = (quad >> 1) != 0;          // nt selector

    // prefetch registers
    short8  pK0, pK1;
    ushort4 pV0, pV1, pV2, pV3;
    {   // load tile 0
        pK0 = *(const short8*)&base[(size_t)kr0 * rs + kcol + kc0];
        pK1 = *(const short8*)&base[(size_t)kr1 * rs + kcol + kc1];
        pV0 = *(const ushort4*)&base[(size_t)(pk + 0) * rs + vcol + pd];
        pV1 = *(const ushort4*)&base[(size_t)(pk + 1) * rs + vcol + pd];
        pV2 = *(const ushort4*)&base[(size_t)(pk + 2) * rs + vcol + pd];
        pV3 = *(const ushort4*)&base[(size_t)(pk + 3) * rs + vcol + pd];
    }

    for (int kt = 0; kt < ktEnd; ++kt) {
        const int kbase = kt * 64;
        const int c = kt & 1;

        // ---- stage prefetched K/V to LDS buf[c] (Vt chunk-swizzled) ----
        *(short8*)&Kh[c][kr0 * KS + kc0] = pK0;
        *(short8*)&Kh[c][kr1 * KS + kc1] = pK1;
        *(ushort4*)&Vt[c][(pd + 0) * KS + vswz] = make_ushort4(pV0.x, pV1.x, pV2.x, pV3.x);
        *(ushort4*)&Vt[c][(pd + 1) * KS + vswz] = make_ushort4(pV0.y, pV1.y, pV2.y, pV3.y);
        *(ushort4*)&Vt[c][(pd + 2) * KS + vswz] = make_ushort4(pV0.z, pV1.z, pV2.z, pV3.z);
        *(ushort4*)&Vt[c][(pd + 3) * KS + vswz] = make_ushort4(pV0.w, pV1.w, pV2.w, pV3.w);
        __syncthreads();   // single barrier per K-tile

        // ---- issue loads for tile kt+1 (fly under compute below) ----
        if (kt + 1 < ktEnd) {
            const int nb = kbase + 64;
            pK0 = *(const short8*)&base[(size_t)(nb + kr0) * rs + kcol + kc0];
            pK1 = *(const short8*)&base[(size_t)(nb + kr1) * rs + kcol + kc1];
            pV0 = *(const ushort4*)&base[(size_t)(nb + pk + 0) * rs + vcol + pd];
            pV1 = *(const ushort4*)&base[(size_t)(nb + pk + 1) * rs + vcol + pd];
            pV2 = *(const ushort4*)&base[(size_t)(nb + pk + 2) * rs + vcol + pd];
            pV3 = *(const ushort4*)&base[(size_t)(nb + pk + 3) * rs + vcol + pd];
        }

        // ---- S'^T = K · (Q*log2e)^T  (swapped operands) ----
        // lane holds S[q=wave*16+m][k=kbase+nt*16+quad*4+r]
        f32x4 S4[4];
#pragma unroll
        for (int nt = 0; nt < 4; ++nt) S4[nt] = zero;
        __builtin_amdgcn_s_setprio(1);
#pragma unroll
        for (int ch = 0; ch < 2; ++ch)
#pragma unroll
            for (int nt = 0; nt < 4; ++nt) {
                const short8 k8 = *(const short8*)&Kh[c][(nt * 16 + m) * KS + ch * 32 + quad * 8];
                S4[nt] = __builtin_amdgcn_mfma_f32_16x16x32_bf16(k8, Qf[ch], S4[nt], 0, 0, 0);
            }
        __builtin_amdgcn_s_setprio(0);

        // ---- mask invalid keys (exp2(-1e30) underflows to exact 0) ----
        if (kbase + 64 > len) {
#pragma unroll
            for (int nt = 0; nt < 4; ++nt)
#pragma unroll
                for (int r = 0; r < 4; ++r)
                    if (kbase + nt * 16 + quad * 4 + r >= len) S4[nt][r] = -1e30f;
        }

        // ---- p = exp2(S'); pack bf16x2 pairs; accumulate row sum ----
        unsigned int pdw[4][2];
#pragma unroll
        for (int nt = 0; nt < 4; ++nt) {
            const float p0 = __builtin_amdgcn_exp2f(S4[nt][0]);
            const float p1 = __builtin_amdgcn_exp2f(S4[nt][1]);
            const float p2 = __builtin_amdgcn_exp2f(S4[nt][2]);
            const float p3 = __builtin_amdgcn_exp2f(S4[nt][3]);
            lsum += (p0 + p1) + (p2 + p3);
            pdw[nt][0] = (unsigned int)f2bf(p0) | ((unsigned int)f2bf(p1) << 16);
            pdw[nt][1] = (unsigned int)f2bf(p2) | ((unsigned int)f2bf(p3) << 16);
        }

        // ---- O += P · V, P fragment assembled in-register via shfl ----
        // frag(ch) dword i: k = ch*32+quad*8+2i..+1, owned by lane
        // (qs + (i>>1))*16 + m at pdw[2*ch + (quad>>1)][i&1].
#pragma unroll
        for (int ch = 0; ch < 2; ++ch) {
            union { unsigned int u[4]; short8 s; } pf;
#pragma unroll
            for (int i = 0; i < 4; ++i) {
                const int src = (qs + (i >> 1)) * 16 + m;
                const unsigned int vA = (unsigned int)__shfl((int)pdw[2 * ch + 0][i & 1], src);
                const unsigned int vB = (unsigned int)__shfl((int)pdw[2 * ch + 1][i & 1], src);
                pf.u[i] = qh ? vB : vA;
            }
            const short8 P8 = pf.s;
            __builtin_amdgcn_s_setprio(1);
#pragma unroll
            for (int nt = 0; nt < 4; ++nt) {
                const int pchunk = ((ch * 4 + quad) ^ ((nt * 4 + (m >> 2)) & 7)) * 8;
                const short8 v8 = *(const short8*)&Vt[c][(nt * 16 + m) * KS + pchunk];
                Oacc[nt] = __builtin_amdgcn_mfma_f32_16x16x32_bf16(P8, v8, Oacc[nt], 0, 0, 0);
            }
            __builtin_amdgcn_s_setprio(0);
        }
    }

    // ---- l: reduce across the 4 quads (each lane owns one q row) ----
    lsum += __shfl_xor(lsum, 16);
    lsum += __shfl_xor(lsum, 32);

    // ---- epilogue: /l, zero invalid q rows, bf16 store ----
#pragma unroll
    for (int r = 0; r < 4; ++r) {
        const int qrow = q0 + wave * 16 + quad * 4 + r;
        const float lr = __shfl(lsum, quad * 4 + r);   // lane (quad*4+r) owns that row
        const size_t ob = (size_t)(b * Tc + qrow) * Dc + hh * DHc + m;
        if (qrow < len) {
            const float inv = 1.0f / lr;
#pragma unroll
            for (int nt = 0; nt < 4; ++nt)
                oh[ob + nt * 16] = f2bf(Oacc[nt][r] * inv);
        } else {
#pragma unroll
            for (int nt = 0; nt < 4; ++nt)
                oh[ob + nt * 16] = 0;
        }
    }
}

// ---------------------------------------------------------------------------
// LN1: (outh,outl) = split_bf16(LN(X + Y) * mask). X,Y fp32.
// Single-pass sum/sumsq (R8-proven).
// ---------------------------------------------------------------------------
__global__ __launch_bounds__(256) void ln_split_kernel(
    const float* __restrict__ X, const float* __restrict__ Y,
    const float* __restrict__ g, const float* __restrict__ beta,
    const int* __restrict__ lengths,
    unsigned short* __restrict__ outh, unsigned short* __restrict__ outl)
{
    __shared__ float red[8];
    const int row = blockIdx.x;
    const int b = row / Tc, t = row % Tc;
    const int len = lengths[b];
    const size_t basei = (size_t)row * Dc;
    const int tid = threadIdx.x;

    if (t >= len) {
        for (int j = tid; j < Dc; j += 256) { outh[basei + j] = 0; outl[basei + j] = 0; }
        return;
    }

    float v[3];
    float s = 0.f, s2 = 0.f;
#pragma unroll
    for (int j = 0; j < 3; ++j) {
        int idx = tid + j * 256;
        v[j] = X[basei + idx] + Y[basei + idx];
        s  += v[j];
        s2 += v[j] * v[j];
    }
    const int lane = tid % 64, wid = tid / 64;
#pragma unroll
    for (int sh = 32; sh >= 1; sh >>= 1) {
        s  += __shfl_xor(s, sh);
        s2 += __shfl_xor(s2, sh);
    }
    if (lane == 0) { red[wid] = s; red[4 + wid] = s2; }
    __syncthreads();
    s  = red[0] + red[1] + red[2] + red[3];
    s2 = red[4] + red[5] + red[6] + red[7];
    const float mu   = s * (1.0f / Dc);
    const float var  = s2 * (1.0f / Dc) - mu * mu;
    const float rstd = rsqrtf(var + 1e-5f);

#pragma unroll
    for (int j = 0; j < 3; ++j) {
        int idx = tid + j * 256;
        const float ov = (v[j] - mu) * rstd * g[idx] + beta[idx];
        unsigned short hh, ll;
        bsplit(ov, hh, ll);
        outh[basei + idx] = hh;
        outl[basei + idx] = ll;
    }
}

// ---------------------------------------------------------------------------
// LN2: out = LN((Xh+Xl) + Y) * mask, fp32 out. Y and out may alias (in-place).
// Single-pass sum/sumsq (R8-proven).
// ---------------------------------------------------------------------------
__global__ __launch_bounds__(256) void ln2_kernel(
    const unsigned short* __restrict__ Xh, const unsigned short* __restrict__ Xl,
    const float* Y,
    const float* __restrict__ g, const float* __restrict__ beta,
    const int* __restrict__ lengths, float* out)
{
    __shared__ float red[8];
    const int row = blockIdx.x;
    const int b = row / Tc, t = row % Tc;
    const int len = lengths[b];
    const size_t basei = (size_t)row * Dc;
    const int tid = threadIdx.x;

    if (t >= len) {
        for (int j = tid; j < Dc; j += 256) out[basei + j] = 0.f;
        return;
    }

    float v[3];
    float s = 0.f, s2 = 0.f;
#pragma unroll
    for (int j = 0; j < 3; ++j) {
        int idx = tid + j * 256;
        v[j] = bf2f(Xh[basei + idx]) + bf2f(Xl[basei + idx]) + Y[basei + idx];
        s  += v[j];
        s2 += v[j] * v[j];
    }
    const int lane = tid % 64, wid = tid / 64;
#pragma unroll
    for (int sh = 32; sh >= 1; sh >>= 1) {
        s  += __shfl_xor(s, sh);
        s2 += __shfl_xor(s2, sh);
    }
    if (lane == 0) { red[wid] = s; red[4 + wid] = s2; }
    __syncthreads();
    s  = red[0] + red[1] + red[2] + red[3];
    s2 = red[4] + red[5] + red[6] + red[7];
    const float mu   = s * (1.0f / Dc);
    const float var  = s2 * (1.0f / Dc) - mu * mu;
    const float rstd = rsqrtf(var + 1e-5f);

#pragma unroll
    for (int j = 0; j < 3; ++j) {
        int idx = tid + j * 256;
        out[basei + idx] = (v[j] - mu) * rstd * g[idx] + beta[idx];
    }
}

// ---------------------------------------------------------------------------
// Workspace plan (bytes; peak 51,904,512 — R0 layout):
//   [0, 18.87M)        : qkvh -> projo fp32 [0,12.58M) -> fH head
//   [18.87M, 25.17M)   : xh -> ah -> fH tail  (fH = [0,25.17M) [4096,3072])
//   [25.17M, 31.46M)   : nh | [31.46M, 37.75M) : nl
//   [37.75M, 41.29M)   : wqkvT | [41.29M, 42.47M) : wprojT
//   [42.47M, 47.19M)   : wfcT  | [47.19M, 51.91M) : woutT
// ---------------------------------------------------------------------------
extern "C" void kernel_launch(void* const* d_in, const int* in_sizes, int n_in,
                              void* d_out, int out_size, void* d_ws, size_t ws_size,
                              hipStream_t stream)
{
    const float* x      = (const float*)d_in[0];
    const int*   lens   = (const int*)  d_in[1];
    const float* w_qkv  = (const float*)d_in[2];
    const float* b_qkv  = (const float*)d_in[3];
    const float* w_proj = (const float*)d_in[4];
    const float* b_proj = (const float*)d_in[5];
    const float* ln1_g  = (const float*)d_in[6];
    const float* ln1_b  = (const float*)d_in[7];
    const float* w_fc   = (const float*)d_in[8];
    const float* b_fc   = (const float*)d_in[9];
    const float* w_out  = (const float*)d_in[10];
    const float* b_out  = (const float*)d_in[11];
    const float* ln2_g  = (const float*)d_in[12];
    const float* ln2_b  = (const float*)d_in[13];

    if (ws_size < 51904512) return;  // -> validation mismatch, not a crash

    char* ws = (char*)d_ws;
    unsigned short* qkvh  = (unsigned short*)(ws + 0);           // [4096,2304]
    unsigned short* xh    = (unsigned short*)(ws + 18874368);    // [4096,768]
    unsigned short* ah    = xh;                                  // attn out (xh dead)
    float*          projo = (float*)(ws + 0);                    // [4096,768] fp32
    unsigned short* fH    = (unsigned short*)(ws + 0);           // [4096,3072]
    unsigned short* nh    = (unsigned short*)(ws + 25165824);    // [4096,768]
    unsigned short* nl    = (unsigned short*)(ws + 31457280);
    unsigned short* wqkvT = (unsigned short*)(ws + 37748736);
    unsigned short* wprojT= (unsigned short*)(ws + 41287680);
    unsigned short* wfcT  = (unsigned short*)(ws + 42467328);
    unsigned short* woutT = (unsigned short*)(ws + 47185920);
    float*          mbuf  = (float*)d_out;

    const dim3 blk(256);

    // 0) fused prepare: x cast + all weight transposes
    prepare_kernel<<<dim3(6528), blk, 0, stream>>>(
        x, w_qkv, w_proj, w_fc, w_out, xh, wqkvT, wprojT, wfcT, woutT);

    // 1) qkv = x @ w_qkv + b_qkv -> bf16  (TM=64/TN=128: 1152 blocks)
    gemm_bf16<64, 128, 3><<<dim3(D3 / 128, M_ROWS / 64), blk, 0, stream>>>(
        xh, wqkvT, b_qkv, nullptr, qkvh, M_ROWS, D3, Dc);

    // 2) attention v9 -> ah (bf16)  (768 blocks)
    flash_attn_bf16<<<dim3(Bc * Hc * (Tc / 64)), blk, 0, stream>>>(qkvh, lens, ah);

    // 3) proj: projo = a @ w_proj + b_proj (fp32)  (TN=64: 768 blocks)
    gemm_bf16<64, 64, 0><<<dim3(Dc / 64, M_ROWS / 64), blk, 0, stream>>>(
        ah, wprojT, b_proj, projo, nullptr, M_ROWS, Dc, Dc);

    // 4) n = LN(x + projo) * mask -> (nh, nl)
    ln_split_kernel<<<dim3(M_ROWS), blk, 0, stream>>>(x, projo, ln1_g, ln1_b, lens, nh, nl);

    // 5) fc: fH = bf16(gelu(n @ w_fc + b_fc))  (TM=64/TN=128: 1536 blocks)
    gemm_bf16<64, 128, 1><<<dim3(D4 / 128, M_ROWS / 64), blk, 0, stream>>>(
        nh, wfcT, b_fc, nullptr, fH, M_ROWS, D4, Dc);

    // 6) m = fH @ w_out + b_out -> d_out (fp32), K=3072  (TN=64: 768 blocks)
    gemm_bf16<64, 64, 0><<<dim3(Dc / 64, M_ROWS / 64), blk, 0, stream>>>(
        fH, woutT, b_out, mbuf, nullptr, M_ROWS, Dc, D4);

    // 7) h = LN((nh+nl) + m) * mask -> d_out (in-place)
    ln2_kernel<<<dim3(M_ROWS), blk, 0, stream>>>(nh, nl, mbuf, ln2_g, ln2_b, lens,
                                                 (float*)d_out);
}